// Round 14
// baseline (3509.346 us; speedup 1.0000x reference)
//
#include <hip/hip_runtime.h>
#include <cstddef>
#include <math.h>

// ---------------- model dims ----------------
#define BB 16
#define HIST 336
#define PRED 48
#define SS 384
#define HH 768
#define NL 12
#define FF_ 3072
#define DIN 481
#define DINP 512
#define NE_ 8
#define VV 40000
#define VVP 40064
#define NT 1024              // tail rows: 16 groups x 64

typedef __attribute__((ext_vector_type(8))) short short8;
typedef __attribute__((ext_vector_type(4))) float f32x4;
struct short4v { short x, y, z, w; };

__device__ __forceinline__ short f2bf(float f) {
    union { float f; unsigned u; } v; v.f = f;
    unsigned r = v.u + 0x7fff + ((v.u >> 16) & 1);
    return (short)(r >> 16);
}
__device__ __forceinline__ float bf2f(short s) {
    union { unsigned u; float f; } v; v.u = ((unsigned)(unsigned short)s) << 16;
    return v.f;
}
// fast gelu (tanh form, one v_exp): max |diff vs exact erf-gelu| ~2e-4 for |x|<6
__device__ __forceinline__ float gelu_fast(float x) {
    const float y = 1.5957691216057308f * (x + 0.044715f * x * x * x);
    const float t = 2.f / (1.f + __expf(y)) - 1.f;
    return 0.5f * x * (1.f - t);
}

using gvoid_t = const __attribute__((address_space(1))) void;
using svoid_t = __attribute__((address_space(3))) void;

// ================= bf16 MFMA GEMM 128x128 (r5-proven structure) ============
// C[N,M] = op(A[N,Kp]_bf16 @ Bt[M,Kp]_bf16^T + bias)
// OP 0: f32; OP 1: gelu f32; OP 4: gelu bf16; OP 5: bf16
// OP 7: bf16 + fused residual (out = bf16(acc + bias + bf2f(resid[row*ldc+col])))
template<int OP, bool SWZ>
__global__ __launch_bounds__(256)
void gemm_bf16(const short* __restrict__ A, const short* __restrict__ Bt,
               const float* __restrict__ bias, const float* __restrict__ bias2,
               const float* __restrict__ bias3,
               void* __restrict__ Cout, const short* __restrict__ resid,
               int Kp, int M, int ldc)
{
    __shared__ short As[2][128 * 64];
    __shared__ short Bs[2][128 * 64];
    const int tid  = threadIdx.x;
    const int lane = tid & 63;
    const int w    = tid >> 6;
    const int wr = w >> 1, wc = w & 1;
    const int lrow = lane & 15, lgrp = lane >> 4;

    int bx = blockIdx.x, by = blockIdx.y;
    if (SWZ) {
        const int nwg = gridDim.x * gridDim.y;
        const int o = blockIdx.y * gridDim.x + blockIdx.x;
        const int xcd = o & 7, k = o >> 3;
        const int q = nwg >> 3, r = nwg & 7;
        const int nid = (xcd < r ? xcd * (q + 1) : r * (q + 1) + (xcd - r) * q) + k;
        bx = nid / gridDim.y;
        by = nid % gridDim.y;
    }
    const size_t rowBase = (size_t)by * 128;
    const size_t colBase = (size_t)bx * 128;

    f32x4 acc[4][4];
    #pragma unroll
    for (int i = 0; i < 4; ++i)
        #pragma unroll
        for (int j = 0; j < 4; ++j)
            acc[i][j] = f32x4{0.f, 0.f, 0.f, 0.f};

    const int nkt = Kp >> 6;

    auto stage = [&](int buf, int kt) {
        const short* Ab = A  + rowBase * Kp + (size_t)kt * 64;
        const short* Bb = Bt + colBase * Kp + (size_t)kt * 64;
        #pragma unroll
        for (int c = 0; c < 4; ++c) {
            const int sidx = (w * 4 + c) * 64 + lane;
            const int r = sidx >> 3, sl = sidx & 7;
            const int sseg = sl ^ (r & 7);
            __builtin_amdgcn_global_load_lds(
                (gvoid_t*)(Ab + (size_t)r * Kp + sseg * 8),
                (svoid_t*)&As[buf][(w * 4 + c) * 512], 16, 0, 0);
            __builtin_amdgcn_global_load_lds(
                (gvoid_t*)(Bb + (size_t)r * Kp + sseg * 8),
                (svoid_t*)&Bs[buf][(w * 4 + c) * 512], 16, 0, 0);
        }
    };

    int cur = 0;
    stage(0, 0);
    __syncthreads();
    for (int kt = 0; kt < nkt; ++kt) {
        if (kt + 1 < nkt) stage(cur ^ 1, kt + 1);
        const short* as = As[cur];
        const short* bs = Bs[cur];
        #pragma unroll
        for (int kk = 0; kk < 2; ++kk) {
            short8 aF[4], bF[4];
            #pragma unroll
            for (int mi = 0; mi < 4; ++mi) {
                const int r = wr * 64 + mi * 16 + lrow;
                const int seg = (kk * 4 + lgrp) ^ (r & 7);
                aF[mi] = *(const short8*)&as[r * 64 + seg * 8];
            }
            #pragma unroll
            for (int ni = 0; ni < 4; ++ni) {
                const int r = wc * 64 + ni * 16 + lrow;
                const int seg = (kk * 4 + lgrp) ^ (r & 7);
                bF[ni] = *(const short8*)&bs[r * 64 + seg * 8];
            }
            #pragma unroll
            for (int mi = 0; mi < 4; ++mi)
                #pragma unroll
                for (int ni = 0; ni < 4; ++ni)
                    acc[mi][ni] = __builtin_amdgcn_mfma_f32_16x16x32_bf16(
                        aF[mi], bF[ni], acc[mi][ni], 0, 0, 0);
        }
        __syncthreads();
        cur ^= 1;
    }

    #pragma unroll
    for (int mi = 0; mi < 4; ++mi) {
        #pragma unroll
        for (int ni = 0; ni < 4; ++ni) {
            const int col = (int)colBase + wc * 64 + ni * 16 + lrow;
            if (col >= M) continue;
            const float* bp = bias; int bc = col;
            if (bias2 && col >= HH) {
                if (col < 2 * HH) { bp = bias2; bc = col - HH; }
                else              { bp = bias3; bc = col - 2 * HH; }
            }
            const float bz = bp[bc];
            #pragma unroll
            for (int j = 0; j < 4; ++j) {
                const size_t row = rowBase + wr * 64 + mi * 16 + lgrp * 4 + j;
                float v = acc[mi][ni][j] + bz;
                if (OP == 1 || OP == 4) v = gelu_fast(v);
                if (OP == 7) v += bf2f(resid[row * ldc + col]);
                if (OP == 4 || OP == 5 || OP == 7)
                    ((short*)Cout)[row * ldc + col] = f2bf(v);
                else
                    ((float*)Cout)[row * ldc + col] = v;
            }
        }
    }
}

// ================= bf16 MFMA flash attention (r5-proven; qt-range) =========
template<int HD>
__global__ __launch_bounds__(256)
void attn_mfma(const short* __restrict__ Qg, const short* __restrict__ Kg,
               const short* __restrict__ Vg, short* __restrict__ Og,
               int nh, int ldq, int qld, int ldo, float scale,
               int qt0, int nqt, int qgrp, int ogrp)
{
    constexpr int NI = HD / 16;
    constexpr int SEGS = HD / 8;
    __shared__ short Qs[64 * 64];
    __shared__ short Ks[64 * 64];
    __shared__ short Vt[64 * 72];
    __shared__ short Ps[4][16 * 80];
    int idx = blockIdx.x;
    const int qt = qt0 + idx % nqt; idx /= nqt;
    const int h = idx % nh; idx /= nh;
    const int b = idx;
    const int tid = threadIdx.x;
    const int lane = tid & 63;
    const int w = tid >> 6;
    const int lrow = lane & 15, lgrp = lane >> 4;

    const size_t qrow0 = (size_t)b * qgrp + (qgrp == SS ? qt * 64 : 0);
    const short* Qbase = Qg + qrow0 * qld + h * HD;
    #pragma unroll
    for (int t = 0; t < 2; ++t) {
        const int i = tid + t * 256;
        const int r = i >> 3, sg = i & 7;
        short8 v = {0, 0, 0, 0, 0, 0, 0, 0};
        if (sg < SEGS) v = *(const short8*)(Qbase + (size_t)r * qld + sg * 8);
        *(short8*)&Qs[r * 64 + (sg ^ (r & 7)) * 8] = v;
    }

    float m_[4], l_[4];
    f32x4 o_[NI];
    #pragma unroll
    for (int j = 0; j < 4; ++j) { m_[j] = -1e30f; l_[j] = 0.f; }
    #pragma unroll
    for (int ni = 0; ni < NI; ++ni) o_[ni] = f32x4{0.f, 0.f, 0.f, 0.f};

    for (int kt = 0; kt < 6; ++kt) {
        const short* Kb2 = Kg + ((size_t)(b * SS + kt * 64)) * ldq + h * HD;
        const short* Vb2 = Vg + ((size_t)(b * SS + kt * 64)) * ldq + h * HD;
        __syncthreads();
        #pragma unroll
        for (int c = 0; c < 2; ++c) {
            const int r = (w * 2 + c) * 8 + (lane >> 3);
            const int sg = (lane & 7) ^ (r & 7);
            __builtin_amdgcn_global_load_lds(
                (gvoid_t*)(Kb2 + (size_t)r * ldq + sg * 8),
                (svoid_t*)&Ks[(w * 2 + c) * 512], 16, 0, 0);
        }
        for (int i = tid; i < 64 * SEGS; i += 256) {
            const int k = i & 63, sg = i >> 6;
            short8 v = *(const short8*)(Vb2 + (size_t)k * ldq + sg * 8);
            #pragma unroll
            for (int j2 = 0; j2 < 8; ++j2)
                Vt[(sg * 8 + j2) * 72 + k] = v[j2];
        }
        __syncthreads();

        f32x4 s[4];
        #pragma unroll
        for (int ni = 0; ni < 4; ++ni) s[ni] = f32x4{0.f, 0.f, 0.f, 0.f};
        __builtin_amdgcn_s_setprio(1);
        #pragma unroll
        for (int kk = 0; kk < 2; ++kk) {
            const int ra = w * 16 + lrow;
            const short8 aF = *(const short8*)&Qs[ra * 64 + ((kk * 4 + lgrp) ^ (ra & 7)) * 8];
            #pragma unroll
            for (int ni = 0; ni < 4; ++ni) {
                const int rb = ni * 16 + lrow;
                const short8 bF = *(const short8*)&Ks[rb * 64 + ((kk * 4 + lgrp) ^ (rb & 7)) * 8];
                s[ni] = __builtin_amdgcn_mfma_f32_16x16x32_bf16(aF, bF, s[ni], 0, 0, 0);
            }
        }
        __builtin_amdgcn_s_setprio(0);
        #pragma unroll
        for (int ni = 0; ni < 4; ++ni)
            #pragma unroll
            for (int j = 0; j < 4; ++j) s[ni][j] *= scale;

        #pragma unroll
        for (int j = 0; j < 4; ++j) {
            float tm = fmaxf(fmaxf(s[0][j], s[1][j]), fmaxf(s[2][j], s[3][j]));
            #pragma unroll
            for (int d = 1; d < 16; d <<= 1) tm = fmaxf(tm, __shfl_xor(tm, d));
            const float mn = fmaxf(m_[j], tm);
            const float r2 = __expf(m_[j] - mn);
            float p[4], ps = 0.f;
            #pragma unroll
            for (int ni = 0; ni < 4; ++ni) { p[ni] = __expf(s[ni][j] - mn); ps += p[ni]; }
            #pragma unroll
            for (int d = 1; d < 16; d <<= 1) ps += __shfl_xor(ps, d);
            l_[j] = l_[j] * r2 + ps;
            m_[j] = mn;
            #pragma unroll
            for (int ni = 0; ni < NI; ++ni) o_[ni][j] *= r2;
            #pragma unroll
            for (int ni = 0; ni < 4; ++ni)
                Ps[w][(lgrp * 4 + j) * 80 + ni * 16 + lrow] = f2bf(p[ni]);
        }

        __builtin_amdgcn_s_setprio(1);
        #pragma unroll
        for (int kk = 0; kk < 2; ++kk) {
            const short8 aP = *(const short8*)&Ps[w][lrow * 80 + kk * 32 + lgrp * 8];
            #pragma unroll
            for (int ni = 0; ni < NI; ++ni) {
                const int d0 = ni * 16 + lrow;
                const short8 bV = *(const short8*)&Vt[d0 * 72 + (kk * 4 + lgrp) * 8];
                o_[ni] = __builtin_amdgcn_mfma_f32_16x16x32_bf16(aP, bV, o_[ni], 0, 0, 0);
            }
        }
        __builtin_amdgcn_s_setprio(0);
    }

    const size_t orow0 = (size_t)b * ogrp + (ogrp == SS ? qt * 64 : 0) + w * 16;
    #pragma unroll
    for (int j = 0; j < 4; ++j) {
        const float inv = 1.f / l_[j];
        #pragma unroll
        for (int ni = 0; ni < NI; ++ni)
            Og[(orow0 + lgrp * 4 + j) * ldo + h * HD + ni * 16 + lrow] =
                f2bf(o_[ni][j] * inv);
    }
}

// ======== batched transpose+cvt: W[K,M] f32 -> Wt[Mp,Kp] bf16, z-batched ====
__global__ __launch_bounds__(256)
void transpose_cvt_b(const float* __restrict__ W, short* __restrict__ Wt,
                     int K, int M, int Kp, size_t sStride, size_t dStride)
{
    __shared__ float tile[32][33];
    const float* src = W + blockIdx.z * sStride;
    short* dst = Wt + blockIdx.z * dStride;
    const int m0 = blockIdx.x * 32, k0 = blockIdx.y * 32;
    const int tx = threadIdx.x, ty = threadIdx.y;
    #pragma unroll
    for (int i = 0; i < 4; ++i) {
        int k = k0 + ty + i * 8, m = m0 + tx;
        tile[ty + i * 8][tx] = (k < K && m < M) ? src[(size_t)k * M + m] : 0.f;
    }
    __syncthreads();
    #pragma unroll
    for (int i = 0; i < 4; ++i) {
        int m = m0 + ty + i * 8, k = k0 + tx;
        dst[(size_t)m * Kp + k] = f2bf(tile[tx][ty + i * 8]);
    }
}

// ======== weight prep: qkv(3) + o + f1 + f2; LAYERS via blockIdx.y ========
__global__ __launch_bounds__(256)
void prep_layer_w(const float* __restrict__ bqA, const float* __restrict__ bkA,
                  const float* __restrict__ bvA, const float* __restrict__ boA,
                  const float* __restrict__ f1A, const float* __restrict__ f2A,
                  short* __restrict__ qkvT, short* __restrict__ oT,
                  short* __restrict__ f1T, short* __restrict__ f2T)
{
    __shared__ float tile[32][33];
    const size_t L = blockIdx.y;
    const float* bq = bqA + L * HH * HH;
    const float* bk = bkA + L * HH * HH;
    const float* bv = bvA + L * HH * HH;
    const float* bo = boA + L * HH * HH;
    const float* f1 = f1A + L * HH * FF_;
    const float* f2 = f2A + L * FF_ * HH;
    short* qT = qkvT + L * 3 * HH * HH;
    short* oT2 = oT + L * HH * HH;
    short* f1T2 = f1T + L * HH * FF_;
    short* f2T2 = f2T + L * FF_ * HH;

    int id = blockIdx.x;
    const float* src; short* dst; int K, M, tm, tk;
    if (id < 1728) {
        const int mat = id / 576, r = id % 576;
        src = mat == 0 ? bq : (mat == 1 ? bk : bv);
        dst = qT + (size_t)mat * HH * HH;
        K = HH; M = HH; tm = r % 24; tk = r / 24;
    } else if (id < 2304) {
        const int r = id - 1728;
        src = bo; dst = oT2; K = HH; M = HH; tm = r % 24; tk = r / 24;
    } else if (id < 4608) {
        const int r = id - 2304;
        src = f1; dst = f1T2; K = HH; M = FF_; tm = r % 96; tk = r / 96;
    } else {
        const int r = id - 4608;
        src = f2; dst = f2T2; K = FF_; M = HH; tm = r % 24; tk = r / 24;
    }
    const int m0 = tm * 32, k0 = tk * 32;
    const int tx = threadIdx.x & 31, ty = threadIdx.x >> 5;
    #pragma unroll
    for (int i = 0; i < 4; ++i) {
        int k = k0 + ty + i * 8, m = m0 + tx;
        tile[ty + i * 8][tx] = src[(size_t)k * M + m];
    }
    __syncthreads();
    #pragma unroll
    for (int i = 0; i < 4; ++i) {
        int m = m0 + ty + i * 8, k = k0 + tx;
        dst[(size_t)m * K + k] = f2bf(tile[tx][ty + i * 8]);
    }
}

// ================= f32 -> bf16 =================
__global__ __launch_bounds__(256)
void cvt_bf16(const float* __restrict__ src, short* __restrict__ dst, int n4)
{
    int i = blockIdx.x * 256 + threadIdx.x;
    if (i >= n4) return;
    float4 v = reinterpret_cast<const float4*>(src)[i];
    short4v o = { f2bf(v.x), f2bf(v.y), f2bf(v.z), f2bf(v.w) };
    reinterpret_cast<short4v*>(dst)[i] = o;
}

// ================= features -> LN -> bf16 x [6144,512] =================
__global__ __launch_bounds__(512)
void build_x(const int* __restrict__ isf, const int* __restrict__ hloc,
             const int* __restrict__ psf,
             const float* __restrict__ dayE, const float* __restrict__ timeE,
             const float* __restrict__ dowE, const float* __restrict__ wdE,
             const float* __restrict__ locE,
             const float* __restrict__ g, const float* __restrict__ b2,
             short* __restrict__ xb)
{
    const int tok = blockIdx.x;
    const int b = tok / SS, s = tok % SS;
    const int tid = threadIdx.x;
    __shared__ float red[512];
    const int* f;
    int loc = -1;
    if (s < HIST) { f = isf + (b * HIST + s) * 6; loc = hloc[b * HIST + s]; }
    else          { f = psf + (b * PRED + (s - HIST)) * 6; }
    float val = 0.f;
    if (tid < DIN) {
        int c = tid;
        if      (c < 64)  val = dayE[f[0] * 64 + c];
        else if (c < 128) val = timeE[f[1] * 64 + (c - 64)];
        else if (c < 192) val = dowE[f[3] * 64 + (c - 128)];
        else if (c < 224) val = wdE[f[4] * 32 + (c - 192)];
        else if (c == 224) val = (float)f[5];
        else val = (loc >= 0) ? locE[(size_t)loc * 256 + (c - 225)] : 0.f;
    }
    red[tid] = (tid < DIN) ? val : 0.f;
    __syncthreads();
    for (int o = 256; o > 0; o >>= 1) { if (tid < o) red[tid] += red[tid + o]; __syncthreads(); }
    float mean = red[0] / (float)DIN;
    __syncthreads();
    float d = (tid < DIN) ? (val - mean) : 0.f;
    red[tid] = d * d;
    __syncthreads();
    for (int o = 256; o > 0; o >>= 1) { if (tid < o) red[tid] += red[tid + o]; __syncthreads(); }
    float rstd = rsqrtf(red[0] / (float)DIN + 1e-5f);
    if (tid < DINP)
        xb[(size_t)tok * DINP + tid] =
            (tid < DIN) ? f2bf((val - mean) * rstd * g[tid] + b2[tid]) : (short)0;
}

// ====== LayerNorm(768), wave-per-row, bf16: out = LN(in1[+in2]) ============
__global__ __launch_bounds__(256)
void ln768b(short* __restrict__ out, const short* __restrict__ in1,
            const short* __restrict__ in2,
            const float* __restrict__ g, const float* __restrict__ b2,
            float eps)
{
    const int w = threadIdx.x >> 6, lane = threadIdx.x & 63;
    const int row = blockIdx.x * 4 + w;
    float t[12];
    float sum = 0.f;
    #pragma unroll
    for (int i = 0; i < 3; ++i) {
        const int c = i * 256 + lane * 4;
        short4v a = *(const short4v*)&in1[(size_t)row * HH + c];
        t[i * 4 + 0] = bf2f(a.x);
        t[i * 4 + 1] = bf2f(a.y);
        t[i * 4 + 2] = bf2f(a.z);
        t[i * 4 + 3] = bf2f(a.w);
        if (in2) {
            short4v b = *(const short4v*)&in2[(size_t)row * HH + c];
            t[i*4+0] += bf2f(b.x); t[i*4+1] += bf2f(b.y);
            t[i*4+2] += bf2f(b.z); t[i*4+3] += bf2f(b.w);
        }
        sum += t[i*4] + t[i*4+1] + t[i*4+2] + t[i*4+3];
    }
    #pragma unroll
    for (int d = 1; d < 64; d <<= 1) sum += __shfl_xor(sum, d);
    const float mean = sum * (1.f / 768.f);
    float p2 = 0.f;
    #pragma unroll
    for (int i = 0; i < 12; ++i) { float d = t[i] - mean; p2 += d * d; }
    #pragma unroll
    for (int d = 1; d < 64; d <<= 1) p2 += __shfl_xor(p2, d);
    const float rstd = rsqrtf(p2 * (1.f / 768.f) + eps);
    #pragma unroll
    for (int i = 0; i < 3; ++i) {
        const int c = i * 256 + lane * 4;
        float4 gg = *(const float4*)&g[c];
        float4 bb = *(const float4*)&b2[c];
        short4v ob = { f2bf((t[i*4+0] - mean) * rstd * gg.x + bb.x),
                       f2bf((t[i*4+1] - mean) * rstd * gg.y + bb.y),
                       f2bf((t[i*4+2] - mean) * rstd * gg.z + bb.z),
                       f2bf((t[i*4+3] - mean) * rstd * gg.w + bb.w) };
        *(short4v*)&out[(size_t)row * HH + c] = ob;
    }
}

// ====== fused double LN: out = LN2(LN1(in1) + pos + tt)  (resid pre-fused) ==
__global__ __launch_bounds__(256)
void ln2_fused(short* __restrict__ out, const short* __restrict__ in1,
               const float* __restrict__ pos, const float* __restrict__ tt,
               const float* __restrict__ g1, const float* __restrict__ b1,
               const float* __restrict__ g2, const float* __restrict__ b2)
{
    const int w = threadIdx.x >> 6, lane = threadIdx.x & 63;
    const int row = blockIdx.x * 4 + w;
    const int s = row % SS;
    float t[12];
    float sum = 0.f;
    #pragma unroll
    for (int i = 0; i < 3; ++i) {
        const int c = i * 256 + lane * 4;
        short4v a = *(const short4v*)&in1[(size_t)row * HH + c];
        t[i*4+0] = bf2f(a.x);
        t[i*4+1] = bf2f(a.y);
        t[i*4+2] = bf2f(a.z);
        t[i*4+3] = bf2f(a.w);
        sum += t[i*4] + t[i*4+1] + t[i*4+2] + t[i*4+3];
    }
    #pragma unroll
    for (int d = 1; d < 64; d <<= 1) sum += __shfl_xor(sum, d);
    float mean = sum * (1.f / 768.f);
    float p2 = 0.f;
    #pragma unroll
    for (int i = 0; i < 12; ++i) { float d = t[i] - mean; p2 += d * d; }
    #pragma unroll
    for (int d = 1; d < 64; d <<= 1) p2 += __shfl_xor(p2, d);
    float rstd = rsqrtf(p2 * (1.f / 768.f) + 1e-5f);
    sum = 0.f;
    #pragma unroll
    for (int i = 0; i < 3; ++i) {
        const int c = i * 256 + lane * 4;
        float4 gg = *(const float4*)&g1[c];
        float4 bb = *(const float4*)&b1[c];
        float4 pp = *(const float4*)&pos[(size_t)s * HH + c];
        float4 tz = *(const float4*)&tt[c];
        t[i*4+0] = (t[i*4+0] - mean) * rstd * gg.x + bb.x + pp.x + tz.x;
        t[i*4+1] = (t[i*4+1] - mean) * rstd * gg.y + bb.y + pp.y + tz.y;
        t[i*4+2] = (t[i*4+2] - mean) * rstd * gg.z + bb.z + pp.z + tz.z;
        t[i*4+3] = (t[i*4+3] - mean) * rstd * gg.w + bb.w + pp.w + tz.w;
        sum += t[i*4] + t[i*4+1] + t[i*4+2] + t[i*4+3];
    }
    #pragma unroll
    for (int d = 1; d < 64; d <<= 1) sum += __shfl_xor(sum, d);
    mean = sum * (1.f / 768.f);
    p2 = 0.f;
    #pragma unroll
    for (int i = 0; i < 12; ++i) { float d = t[i] - mean; p2 += d * d; }
    #pragma unroll
    for (int d = 1; d < 64; d <<= 1) p2 += __shfl_xor(p2, d);
    rstd = rsqrtf(p2 * (1.f / 768.f) + 1e-12f);
    #pragma unroll
    for (int i = 0; i < 3; ++i) {
        const int c = i * 256 + lane * 4;
        float4 gg = *(const float4*)&g2[c];
        float4 bb = *(const float4*)&b2[c];
        short4v ob = { f2bf((t[i*4+0] - mean) * rstd * gg.x + bb.x),
                       f2bf((t[i*4+1] - mean) * rstd * gg.y + bb.y),
                       f2bf((t[i*4+2] - mean) * rstd * gg.z + bb.z),
                       f2bf((t[i*4+3] - mean) * rstd * gg.w + bb.w) };
        *(short4v*)&out[(size_t)row * HH + c] = ob;
    }
}

// ==== row gather: dst[r] = src[(r/dstGroup)*srcGroup + srcOff + r%dstGroup] =
__global__ void gather_rows_b16(const short* __restrict__ src, short* __restrict__ dst,
                                int D, int srcGroup, int srcOff, int dstGroup)
{
    const int r = blockIdx.x;
    const int b = r / dstGroup, t = r % dstGroup;
    const int srow = b * srcGroup + srcOff + t;
    for (int c = threadIdx.x; c < D; c += blockDim.x)
        dst[(size_t)r * D + c] = src[(size_t)srow * D + c];
}

// ================= gate (bf16 input) =================
__global__ __launch_bounds__(256)
void gate_kernel(const short* __restrict__ Xb, const float* __restrict__ Wg,
                 const float* __restrict__ bg, float* __restrict__ out)
{
    const int row = blockIdx.x;
    const int tid = threadIdx.x;
    float a[NE_] = {};
    for (int k = tid; k < HH; k += 256) {
        float xv = bf2f(Xb[(size_t)row * HH + k]);
        #pragma unroll
        for (int e = 0; e < NE_; ++e) a[e] = fmaf(xv, Wg[k * NE_ + e], a[e]);
    }
    __shared__ float red[256];
    #pragma unroll
    for (int e = 0; e < NE_; ++e) {
        red[tid] = a[e]; __syncthreads();
        for (int o = 128; o > 0; o >>= 1) { if (tid < o) red[tid] += red[tid + o]; __syncthreads(); }
        if (tid == 0) out[(size_t)row * NE_ + e] = red[0] + bg[e];
        __syncthreads();
    }
}

__global__ void gate_softmax(float* __restrict__ gate)
{
    const int r = blockIdx.x * blockDim.x + threadIdx.x;
    if (r >= BB * PRED) return;
    float* p = gate + (size_t)r * NE_;
    float mx = p[0];
    for (int e = 1; e < NE_; ++e) mx = fmaxf(mx, p[e]);
    float s = 0.f, v[NE_];
    for (int e = 0; e < NE_; ++e) { v[e] = __expf(p[e] - mx); s += v[e]; }
    for (int e = 0; e < NE_; ++e) p[e] = v[e] / s;
}

// ============ MoE gated reduce: futm += sum_e g[e]*eo[row][e*768+c] ========
__global__ __launch_bounds__(256)
void moe_reduce(const float* __restrict__ eo, const float* __restrict__ gp,
                float* __restrict__ futm)
{
    const int row = blockIdx.x;
    float g[NE_];
    #pragma unroll
    for (int e = 0; e < NE_; ++e) g[e] = gp[row * NE_ + e];
    for (int c = threadIdx.x; c < HH; c += 256) {
        float s = futm[(size_t)row * HH + c];
        #pragma unroll
        for (int e = 0; e < NE_; ++e)
            s = fmaf(g[e], eo[(size_t)row * (NE_ * HH) + e * HH + c], s);
        futm[(size_t)row * HH + c] = s;
    }
}

// ================= host =================
extern "C" void kernel_launch(void* const* d_in, const int* in_sizes, int n_in,
                              void* d_out, int out_size, void* d_ws, size_t ws_size,
                              hipStream_t stream)
{
    const int*   isf   = (const int*)  d_in[0];
    const int*   hloc  = (const int*)  d_in[1];
    const int*   psf   = (const int*)  d_in[2];
    const float* dayE  = (const float*)d_in[3];
    const float* timeE = (const float*)d_in[4];
    const float* dowE  = (const float*)d_in[5];
    const float* wdE   = (const float*)d_in[6];
    const float* locE  = (const float*)d_in[7];
    const float* ln_g  = (const float*)d_in[8];
    const float* ln_b  = (const float*)d_in[9];
    const float* inpW  = (const float*)d_in[10];
    const float* inpB  = (const float*)d_in[11];
    const float* resW  = (const float*)d_in[12];
    const float* resB  = (const float*)d_in[13];
    const float* saqW  = (const float*)d_in[14];
    const float* sakW  = (const float*)d_in[15];
    const float* savW  = (const float*)d_in[16];
    const float* saoW  = (const float*)d_in[17];
    const float* saqB  = (const float*)d_in[18];
    const float* sakB  = (const float*)d_in[19];
    const float* savB  = (const float*)d_in[20];
    const float* saoB  = (const float*)d_in[21];
    const float* salnG = (const float*)d_in[22];
    const float* salnB = (const float*)d_in[23];
    const float* posE  = (const float*)d_in[24];
    const float* ttE   = (const float*)d_in[25];
    const float* belnG = (const float*)d_in[26];
    const float* belnB = (const float*)d_in[27];
    const float* bqW   = (const float*)d_in[28];
    const float* bkW   = (const float*)d_in[29];
    const float* bvW   = (const float*)d_in[30];
    const float* boW   = (const float*)d_in[31];
    const float* bqB   = (const float*)d_in[32];
    const float* bkB   = (const float*)d_in[33];
    const float* bvB   = (const float*)d_in[34];
    const float* boB   = (const float*)d_in[35];
    const float* balnG = (const float*)d_in[36];
    const float* balnB = (const float*)d_in[37];
    const float* bf1W  = (const float*)d_in[38];
    const float* bf1B  = (const float*)d_in[39];
    const float* bf2W  = (const float*)d_in[40];
    const float* bf2B  = (const float*)d_in[41];
    const float* bflnG = (const float*)d_in[42];
    const float* bflnB = (const float*)d_in[43];
    const float* moeW  = (const float*)d_in[44];
    const float* moeB  = (const float*)d_in[45];
    const float* gateW = (const float*)d_in[46];
    const float* gateB = (const float*)d_in[47];
    const float* outW  = (const float*)d_in[48];
    const float* outB  = (const float*)d_in[49];

    const int N6 = BB * SS;            // 6144
    const int NF = BB * PRED;          // 768

    char* base = (char*)d_ws;
    size_t off = 0;
    auto alloc = [&](size_t bytes) -> void* {
        void* p = base + off;
        off = (off + bytes + 255) & ~(size_t)255;
        return p;
    };

    short* xb   = (short*)alloc((size_t)N6 * DINP * 2);
    short* pb   = (short*)alloc((size_t)N6 * HH * 2);   // proj out / SA residual
    short* ab   = (short*)alloc((size_t)N6 * HH * 2);   // post-attn LN out
    short* Ob   = (short*)alloc((size_t)N6 * HH * 2);
    short* hcur = (short*)alloc((size_t)N6 * HH * 2);
    // --- contiguous trio reused as overlay after encoder (75.5MB) ---
    short* QKVb = (short*)alloc((size_t)N6 * 3 * HH * 2);
    short* C16  = (short*)alloc((size_t)N6 * HH * 2);
    short* ffb  = (short*)alloc((size_t)N6 * FF_ * 2);
    // ----------------------------------------------------------------
    short* inpWt  = (short*)alloc((size_t)HH * DINP * 2);
    short* resWt  = (short*)alloc((size_t)HH * DINP * 2);
    short* saWt   = (short*)alloc((size_t)3 * HH * HH * 2);
    short* saoWt  = (short*)alloc((size_t)HH * HH * 2);
    short* lqkvWt = (short*)alloc((size_t)3 * HH * HH * 2);
    short* loWt   = (short*)alloc((size_t)HH * HH * 2);
    short* lf1Wt  = (short*)alloc((size_t)FF_ * HH * 2);
    short* lf2Wt  = (short*)alloc((size_t)HH * FF_ * 2);
    float* futm   = (float*)alloc((size_t)NF * HH * 4);
    float* futg   = (float*)alloc((size_t)NF * NE_ * 4);
    // tail (layer-12 future-only) buffers, N=1024 rows
    short* Og   = (short*)alloc((size_t)NT * HH * 2);
    short* hg   = (short*)alloc((size_t)NT * HH * 2);
    short* Cg   = (short*)alloc((size_t)NT * HH * 2);
    short* ag   = (short*)alloc((size_t)NT * HH * 2);
    short* hfg  = (short*)alloc((size_t)NT * HH * 2);
    short* ffg  = (short*)alloc((size_t)NT * FF_ * 2);

    const size_t perL = ((size_t)3*HH*HH + (size_t)HH*HH + (size_t)HH*FF_ + (size_t)FF_*HH) * 2;
    short* LqkvA = nullptr; short* LoA = nullptr; short* Lf1A = nullptr; short* Lf2A = nullptr;
    bool upfront = false;
    if (ws_size > off + 12 * perL + (32u << 20)) {
        LqkvA = (short*)alloc((size_t)12 * 3 * HH * HH * 2);
        LoA   = (short*)alloc((size_t)12 * HH * HH * 2);
        Lf1A  = (short*)alloc((size_t)12 * HH * FF_ * 2);
        Lf2A  = (short*)alloc((size_t)12 * FF_ * HH * 2);
        upfront = true;
    }

    // overlay (post-encoder) inside QKVb..ffb
    short* outWt = QKVb;                              // [40064][768]
    short* moeWt = outWt + (size_t)VVP * HH;          // [6144][768]
    short* futhb = moeWt + (size_t)NE_ * HH * HH;
    short* futxb = futhb + (size_t)NF * HH;
    short* futmb = futxb + (size_t)NF * DINP;
    float* eoF   = (float*)pb;                        // [768][6144] f32

    // ---- features + input LN -> bf16 x ----
    build_x<<<N6, 512, 0, stream>>>(isf, hloc, psf, dayE, timeE, dowE, wdE, locE,
                                    ln_g, ln_b, xb);

    // ---- upfront weight prep ----
    dim3 tb(32, 8);
    transpose_cvt_b<<<dim3(HH/32, DINP/32, 1), tb, 0, stream>>>(inpW, inpWt, DIN, HH, DINP, 0, 0);
    transpose_cvt_b<<<dim3(HH/32, DINP/32, 1), tb, 0, stream>>>(resW, resWt, DIN, HH, DINP, 0, 0);
    transpose_cvt_b<<<dim3(HH/32, HH/32, 1), tb, 0, stream>>>(saqW, saWt,                   HH, HH, HH, 0, 0);
    transpose_cvt_b<<<dim3(HH/32, HH/32, 1), tb, 0, stream>>>(sakW, saWt + (size_t)HH*HH,   HH, HH, HH, 0, 0);
    transpose_cvt_b<<<dim3(HH/32, HH/32, 1), tb, 0, stream>>>(savW, saWt + (size_t)2*HH*HH, HH, HH, HH, 0, 0);
    transpose_cvt_b<<<dim3(HH/32, HH/32, 1), tb, 0, stream>>>(saoW, saoWt, HH, HH, HH, 0, 0);
    if (upfront)
        prep_layer_w<<<dim3(6912, 12), 256, 0, stream>>>(
            bqW, bkW, bvW, boW, bf1W, bf2W, LqkvA, LoA, Lf1A, Lf2A);

    // ---- proj = LN(x) @ inpW -> pb (bf16) ----
    gemm_bf16<5, false><<<dim3(HH/128, N6/128), 256, 0, stream>>>(
        xb, inpWt, inpB, nullptr, nullptr, pb, nullptr, DINP, HH, HH);

    // ---- SA block (16 heads, hd=48) ----
    gemm_bf16<5, false><<<dim3(3*HH/128, N6/128), 256, 0, stream>>>(
        pb, saWt, saqB, sakB, savB, QKVb, nullptr, HH, 3*HH, 3*HH);
    attn_mfma<48><<<BB*16*6, 256, 0, stream>>>(
        QKVb, QKVb + HH, QKVb + 2*HH, Ob, 16, 3*HH, 3*HH, HH,
        1.f / sqrtf(48.f), 0, 6, SS, SS);
    gemm_bf16<7, false><<<dim3(HH/128, N6/128), 256, 0, stream>>>(
        Ob, saoWt, saoB, nullptr, nullptr, C16, pb, HH, HH, HH);
    ln2_fused<<<N6/4, 256, 0, stream>>>(hcur, C16, posE, ttE,
                                        salnG, salnB, belnG, belnB);

    // ---- 12 encoder layers (last layer: future-rows-only tail) ----
    for (int i = 0; i < NL; ++i) {
        const size_t bo = (size_t)i * HH;
        const short* wQ; const short* wO; const short* wF1; const short* wF2;
        if (upfront) {
            wQ  = LqkvA + (size_t)i * 3 * HH * HH;
            wO  = LoA   + (size_t)i * HH * HH;
            wF1 = Lf1A  + (size_t)i * HH * FF_;
            wF2 = Lf2A  + (size_t)i * FF_ * HH;
        } else {
            prep_layer_w<<<dim3(6912, 1), 256, 0, stream>>>(
                bqW + (size_t)i*HH*HH, bkW + (size_t)i*HH*HH, bvW + (size_t)i*HH*HH,
                boW + (size_t)i*HH*HH, bf1W + (size_t)i*HH*FF_, bf2W + (size_t)i*FF_*HH,
                lqkvWt, loWt, lf1Wt, lf2Wt);
            wQ = lqkvWt; wO = loWt; wF1 = lf1Wt; wF2 = lf2Wt;
        }

        if (i < NL - 1) {
            gemm_bf16<5, false><<<dim3(3*HH/128, N6/128), 256, 0, stream>>>(
                hcur, wQ, bqB + bo, bkB + bo, bvB + bo, QKVb, nullptr, HH, 3*HH, 3*HH);
            attn_mfma<64><<<BB*12*6, 256, 0, stream>>>(
                QKVb, QKVb + HH, QKVb + 2*HH, Ob, 12, 3*HH, 3*HH, HH,
                0.125f, 0, 6, SS, SS);
            gemm_bf16<7, false><<<dim3(HH/128, N6/128), 256, 0, stream>>>(
                Ob, wO, boB + bo, nullptr, nullptr, C16, hcur, HH, HH, HH);
            ln768b<<<N6/4, 256, 0, stream>>>(ab, C16, nullptr, balnG + bo, balnB + bo, 1e-12f);
            gemm_bf16<4, false><<<dim3(FF_/128, N6/128), 256, 0, stream>>>(
                ab, wF1, bf1B + (size_t)i * FF_, nullptr, nullptr, ffb, nullptr, HH, FF_, FF_);
            gemm_bf16<7, false><<<dim3(HH/128, N6/128), 256, 0, stream>>>(
                ffb, wF2, bf2B + bo, nullptr, nullptr, C16, ab, FF_, HH, HH);
            ln768b<<<N6/4, 256, 0, stream>>>(hcur, C16, nullptr, bflnG + bo, bflnB + bo, 1e-12f);
        } else {
            // last layer: Q only for tail rows; K/V for ALL tokens
            gather_rows_b16<<<NT, 256, 0, stream>>>(hcur, hg, HH, SS, 320, 64);
            gemm_bf16<5, false><<<dim3(2*HH/128, N6/128), 256, 0, stream>>>(
                hcur, wQ + (size_t)HH*HH, bkB + bo, bvB + bo, bvB + bo,
                QKVb, nullptr, HH, 2*HH, 2*HH);
            gemm_bf16<5, false><<<dim3(HH/128, NT/128), 256, 0, stream>>>(
                hg, wQ, bqB + bo, nullptr, nullptr, ag, nullptr, HH, HH, HH);
            attn_mfma<64><<<BB*12*1, 256, 0, stream>>>(
                ag, QKVb, QKVb + HH, Og, 12, 2*HH, HH, HH,
                0.125f, 0, 1, 64, 64);
            gemm_bf16<7, false><<<dim3(HH/128, NT/128), 256, 0, stream>>>(
                Og, wO, boB + bo, nullptr, nullptr, Cg, hg, HH, HH, HH);
            ln768b<<<NT/4, 256, 0, stream>>>(ag, Cg, nullptr, balnG + bo, balnB + bo, 1e-12f);
            gemm_bf16<4, false><<<dim3(FF_/128, NT/128), 256, 0, stream>>>(
                ag, wF1, bf1B + (size_t)i * FF_, nullptr, nullptr, ffg, nullptr, HH, FF_, FF_);
            gemm_bf16<7, false><<<dim3(HH/128, NT/128), 256, 0, stream>>>(
                ffg, wF2, bf2B + bo, nullptr, nullptr, Cg, ag, FF_, HH, HH);
            ln768b<<<NT/4, 256, 0, stream>>>(hfg, Cg, nullptr, bflnG + bo, bflnB + bo, 1e-12f);
        }
    }

    // ---- future slice: hfg rows b*64 + 16 + t  (t = 0..47) ----
    gather_rows_b16<<<NF, 256, 0, stream>>>(hfg, futhb, HH, 64, 16, PRED);
    gather_rows_b16<<<NF, 256, 0, stream>>>(xb, futxb, DINP, SS, HIST, PRED);

    // ---- residual path (f32 accumulator) ----
    gemm_bf16<0, false><<<dim3(HH/128, NF/128), 256, 0, stream>>>(
        futxb, resWt, resB, nullptr, nullptr, futm, nullptr, DINP, HH, HH);

    // ---- gate ----
    gate_kernel<<<NF, 256, 0, stream>>>(futhb, gateW, gateB, futg);
    gate_softmax<<<3, 256, 0, stream>>>(futg);

    // ---- MoE: 8 experts fused -> eoF (pb region, dead) ----
    transpose_cvt_b<<<dim3(HH/32, HH/32, NE_), tb, 0, stream>>>(
        moeW, moeWt, HH, HH, HH, (size_t)HH*HH, (size_t)HH*HH);
    gemm_bf16<1, true><<<dim3(NE_*HH/128, NF/128), 256, 0, stream>>>(
        futhb, moeWt, moeB, nullptr, nullptr, eoF, nullptr, HH, NE_*HH, NE_*HH);
    moe_reduce<<<NF, 256, 0, stream>>>(eoF, futg, futm);

    // ---- head: logits for future tokens ----
    {
        int n4 = (int)((size_t)NF * HH / 4);
        cvt_bf16<<<(n4 + 255) / 256, 256, 0, stream>>>(futm, futmb, n4);
    }
    transpose_cvt_b<<<dim3(VVP/32, HH/32, 1), tb, 0, stream>>>(
        outW, outWt, HH, VV, HH, 0, 0);
    gemm_bf16<0, true><<<dim3(VVP/128, NF/128), 256, 0, stream>>>(
        futmb, outWt, outB, nullptr, nullptr, (float*)d_out, nullptr, HH, VV, VV);
}

// Round 15
// 3453.664 us; speedup vs baseline: 1.0161x; 1.0161x over previous
//
#include <hip/hip_runtime.h>
#include <cstddef>
#include <math.h>

// ---------------- model dims ----------------
#define BB 16
#define HIST 336
#define PRED 48
#define SS 384
#define HH 768
#define NL 12
#define FF_ 3072
#define DIN 481
#define DINP 512
#define NE_ 8
#define VV 40000
#define VVP 40064
#define NT 1024              // tail rows: 16 groups x 64

typedef __attribute__((ext_vector_type(8))) short short8;
typedef __attribute__((ext_vector_type(4))) float f32x4;
struct short4v { short x, y, z, w; };

__device__ __forceinline__ short f2bf(float f) {
    union { float f; unsigned u; } v; v.f = f;
    unsigned r = v.u + 0x7fff + ((v.u >> 16) & 1);
    return (short)(r >> 16);
}
__device__ __forceinline__ float bf2f(short s) {
    union { unsigned u; float f; } v; v.u = ((unsigned)(unsigned short)s) << 16;
    return v.f;
}
// fast gelu (tanh form, one v_exp): max |diff vs exact erf-gelu| ~2e-4 for |x|<6
__device__ __forceinline__ float gelu_fast(float x) {
    const float y = 1.5957691216057308f * (x + 0.044715f * x * x * x);
    const float t = 2.f / (1.f + __expf(y)) - 1.f;
    return 0.5f * x * (1.f - t);
}

using gvoid_t = const __attribute__((address_space(1))) void;
using svoid_t = __attribute__((address_space(3))) void;

// ================= bf16 MFMA GEMM 128x128 (r5-proven structure) ============
// C[N,M] = op(A[N,Kp]_bf16 @ Bt[M,Kp]_bf16^T + bias)
// OP 0: f32; OP 1: gelu f32; OP 4: gelu bf16; OP 5: bf16
template<int OP, bool SWZ>
__global__ __launch_bounds__(256)
void gemm_bf16(const short* __restrict__ A, const short* __restrict__ Bt,
               const float* __restrict__ bias, const float* __restrict__ bias2,
               const float* __restrict__ bias3,
               void* __restrict__ Cout, int Kp, int M, int ldc)
{
    __shared__ short As[2][128 * 64];
    __shared__ short Bs[2][128 * 64];
    const int tid  = threadIdx.x;
    const int lane = tid & 63;
    const int w    = tid >> 6;
    const int wr = w >> 1, wc = w & 1;
    const int lrow = lane & 15, lgrp = lane >> 4;

    int bx = blockIdx.x, by = blockIdx.y;
    if (SWZ) {
        const int nwg = gridDim.x * gridDim.y;
        const int o = blockIdx.y * gridDim.x + blockIdx.x;
        const int xcd = o & 7, k = o >> 3;
        const int q = nwg >> 3, r = nwg & 7;
        const int nid = (xcd < r ? xcd * (q + 1) : r * (q + 1) + (xcd - r) * q) + k;
        bx = nid / gridDim.y;
        by = nid % gridDim.y;
    }
    const size_t rowBase = (size_t)by * 128;
    const size_t colBase = (size_t)bx * 128;

    f32x4 acc[4][4];
    #pragma unroll
    for (int i = 0; i < 4; ++i)
        #pragma unroll
        for (int j = 0; j < 4; ++j)
            acc[i][j] = f32x4{0.f, 0.f, 0.f, 0.f};

    const int nkt = Kp >> 6;

    auto stage = [&](int buf, int kt) {
        const short* Ab = A  + rowBase * Kp + (size_t)kt * 64;
        const short* Bb = Bt + colBase * Kp + (size_t)kt * 64;
        #pragma unroll
        for (int c = 0; c < 4; ++c) {
            const int sidx = (w * 4 + c) * 64 + lane;
            const int r = sidx >> 3, sl = sidx & 7;
            const int sseg = sl ^ (r & 7);
            __builtin_amdgcn_global_load_lds(
                (gvoid_t*)(Ab + (size_t)r * Kp + sseg * 8),
                (svoid_t*)&As[buf][(w * 4 + c) * 512], 16, 0, 0);
            __builtin_amdgcn_global_load_lds(
                (gvoid_t*)(Bb + (size_t)r * Kp + sseg * 8),
                (svoid_t*)&Bs[buf][(w * 4 + c) * 512], 16, 0, 0);
        }
    };

    int cur = 0;
    stage(0, 0);
    __syncthreads();
    for (int kt = 0; kt < nkt; ++kt) {
        if (kt + 1 < nkt) stage(cur ^ 1, kt + 1);
        const short* as = As[cur];
        const short* bs = Bs[cur];
        #pragma unroll
        for (int kk = 0; kk < 2; ++kk) {
            short8 aF[4], bF[4];
            #pragma unroll
            for (int mi = 0; mi < 4; ++mi) {
                const int r = wr * 64 + mi * 16 + lrow;
                const int seg = (kk * 4 + lgrp) ^ (r & 7);
                aF[mi] = *(const short8*)&as[r * 64 + seg * 8];
            }
            #pragma unroll
            for (int ni = 0; ni < 4; ++ni) {
                const int r = wc * 64 + ni * 16 + lrow;
                const int seg = (kk * 4 + lgrp) ^ (r & 7);
                bF[ni] = *(const short8*)&bs[r * 64 + seg * 8];
            }
            #pragma unroll
            for (int mi = 0; mi < 4; ++mi)
                #pragma unroll
                for (int ni = 0; ni < 4; ++ni)
                    acc[mi][ni] = __builtin_amdgcn_mfma_f32_16x16x32_bf16(
                        aF[mi], bF[ni], acc[mi][ni], 0, 0, 0);
        }
        __syncthreads();
        cur ^= 1;
    }

    #pragma unroll
    for (int mi = 0; mi < 4; ++mi) {
        #pragma unroll
        for (int ni = 0; ni < 4; ++ni) {
            const int col = (int)colBase + wc * 64 + ni * 16 + lrow;
            if (col >= M) continue;
            const float* bp = bias; int bc = col;
            if (bias2 && col >= HH) {
                if (col < 2 * HH) { bp = bias2; bc = col - HH; }
                else              { bp = bias3; bc = col - 2 * HH; }
            }
            const float bz = bp[bc];
            #pragma unroll
            for (int j = 0; j < 4; ++j) {
                const size_t row = rowBase + wr * 64 + mi * 16 + lgrp * 4 + j;
                float v = acc[mi][ni][j] + bz;
                if (OP == 1 || OP == 4) v = gelu_fast(v);
                if (OP == 4 || OP == 5) ((short*)Cout)[row * ldc + col] = f2bf(v);
                else                    ((float*)Cout)[row * ldc + col] = v;
            }
        }
    }
}

// ================= bf16 MFMA flash attention (r5-proven; qt-range) =========
// qld/qgrp: Q buffer leading dim and rows-per-batch group (SS normal, 64 tail)
// ogrp: output rows-per-batch group. K/V use ldq, full SS rows always.
template<int HD>
__global__ __launch_bounds__(256)
void attn_mfma(const short* __restrict__ Qg, const short* __restrict__ Kg,
               const short* __restrict__ Vg, short* __restrict__ Og,
               int nh, int ldq, int qld, int ldo, float scale,
               int qt0, int nqt, int qgrp, int ogrp)
{
    constexpr int NI = HD / 16;
    constexpr int SEGS = HD / 8;
    __shared__ short Qs[64 * 64];
    __shared__ short Ks[64 * 64];
    __shared__ short Vt[64 * 72];
    __shared__ short Ps[4][16 * 80];
    int idx = blockIdx.x;
    const int qt = qt0 + idx % nqt; idx /= nqt;
    const int h = idx % nh; idx /= nh;
    const int b = idx;
    const int tid = threadIdx.x;
    const int lane = tid & 63;
    const int w = tid >> 6;
    const int lrow = lane & 15, lgrp = lane >> 4;

    const size_t qrow0 = (size_t)b * qgrp + (qgrp == SS ? qt * 64 : 0);
    const short* Qbase = Qg + qrow0 * qld + h * HD;
    #pragma unroll
    for (int t = 0; t < 2; ++t) {
        const int i = tid + t * 256;
        const int r = i >> 3, sg = i & 7;
        short8 v = {0, 0, 0, 0, 0, 0, 0, 0};
        if (sg < SEGS) v = *(const short8*)(Qbase + (size_t)r * qld + sg * 8);
        *(short8*)&Qs[r * 64 + (sg ^ (r & 7)) * 8] = v;
    }

    float m_[4], l_[4];
    f32x4 o_[NI];
    #pragma unroll
    for (int j = 0; j < 4; ++j) { m_[j] = -1e30f; l_[j] = 0.f; }
    #pragma unroll
    for (int ni = 0; ni < NI; ++ni) o_[ni] = f32x4{0.f, 0.f, 0.f, 0.f};

    for (int kt = 0; kt < 6; ++kt) {
        const short* Kb2 = Kg + ((size_t)(b * SS + kt * 64)) * ldq + h * HD;
        const short* Vb2 = Vg + ((size_t)(b * SS + kt * 64)) * ldq + h * HD;
        __syncthreads();
        #pragma unroll
        for (int c = 0; c < 2; ++c) {
            const int r = (w * 2 + c) * 8 + (lane >> 3);
            const int sg = (lane & 7) ^ (r & 7);
            __builtin_amdgcn_global_load_lds(
                (gvoid_t*)(Kb2 + (size_t)r * ldq + sg * 8),
                (svoid_t*)&Ks[(w * 2 + c) * 512], 16, 0, 0);
        }
        for (int i = tid; i < 64 * SEGS; i += 256) {
            const int k = i & 63, sg = i >> 6;
            short8 v = *(const short8*)(Vb2 + (size_t)k * ldq + sg * 8);
            #pragma unroll
            for (int j2 = 0; j2 < 8; ++j2)
                Vt[(sg * 8 + j2) * 72 + k] = v[j2];
        }
        __syncthreads();

        f32x4 s[4];
        #pragma unroll
        for (int ni = 0; ni < 4; ++ni) s[ni] = f32x4{0.f, 0.f, 0.f, 0.f};
        __builtin_amdgcn_s_setprio(1);
        #pragma unroll
        for (int kk = 0; kk < 2; ++kk) {
            const int ra = w * 16 + lrow;
            const short8 aF = *(const short8*)&Qs[ra * 64 + ((kk * 4 + lgrp) ^ (ra & 7)) * 8];
            #pragma unroll
            for (int ni = 0; ni < 4; ++ni) {
                const int rb = ni * 16 + lrow;
                const short8 bF = *(const short8*)&Ks[rb * 64 + ((kk * 4 + lgrp) ^ (rb & 7)) * 8];
                s[ni] = __builtin_amdgcn_mfma_f32_16x16x32_bf16(aF, bF, s[ni], 0, 0, 0);
            }
        }
        __builtin_amdgcn_s_setprio(0);
        #pragma unroll
        for (int ni = 0; ni < 4; ++ni)
            #pragma unroll
            for (int j = 0; j < 4; ++j) s[ni][j] *= scale;

        #pragma unroll
        for (int j = 0; j < 4; ++j) {
            float tm = fmaxf(fmaxf(s[0][j], s[1][j]), fmaxf(s[2][j], s[3][j]));
            #pragma unroll
            for (int d = 1; d < 16; d <<= 1) tm = fmaxf(tm, __shfl_xor(tm, d));
            const float mn = fmaxf(m_[j], tm);
            const float r2 = __expf(m_[j] - mn);
            float p[4], ps = 0.f;
            #pragma unroll
            for (int ni = 0; ni < 4; ++ni) { p[ni] = __expf(s[ni][j] - mn); ps += p[ni]; }
            #pragma unroll
            for (int d = 1; d < 16; d <<= 1) ps += __shfl_xor(ps, d);
            l_[j] = l_[j] * r2 + ps;
            m_[j] = mn;
            #pragma unroll
            for (int ni = 0; ni < NI; ++ni) o_[ni][j] *= r2;
            #pragma unroll
            for (int ni = 0; ni < 4; ++ni)
                Ps[w][(lgrp * 4 + j) * 80 + ni * 16 + lrow] = f2bf(p[ni]);
        }

        __builtin_amdgcn_s_setprio(1);
        #pragma unroll
        for (int kk = 0; kk < 2; ++kk) {
            const short8 aP = *(const short8*)&Ps[w][lrow * 80 + kk * 32 + lgrp * 8];
            #pragma unroll
            for (int ni = 0; ni < NI; ++ni) {
                const int d0 = ni * 16 + lrow;
                const short8 bV = *(const short8*)&Vt[d0 * 72 + (kk * 4 + lgrp) * 8];
                o_[ni] = __builtin_amdgcn_mfma_f32_16x16x32_bf16(aP, bV, o_[ni], 0, 0, 0);
            }
        }
        __builtin_amdgcn_s_setprio(0);
    }

    const size_t orow0 = (size_t)b * ogrp + (ogrp == SS ? qt * 64 : 0) + w * 16;
    #pragma unroll
    for (int j = 0; j < 4; ++j) {
        const float inv = 1.f / l_[j];
        #pragma unroll
        for (int ni = 0; ni < NI; ++ni)
            Og[(orow0 + lgrp * 4 + j) * ldo + h * HD + ni * 16 + lrow] =
                f2bf(o_[ni][j] * inv);
    }
}

// ======== batched transpose+cvt: W[K,M] f32 -> Wt[Mp,Kp] bf16, z-batched ====
__global__ __launch_bounds__(256)
void transpose_cvt_b(const float* __restrict__ W, short* __restrict__ Wt,
                     int K, int M, int Kp, size_t sStride, size_t dStride)
{
    __shared__ float tile[32][33];
    const float* src = W + blockIdx.z * sStride;
    short* dst = Wt + blockIdx.z * dStride;
    const int m0 = blockIdx.x * 32, k0 = blockIdx.y * 32;
    const int tx = threadIdx.x, ty = threadIdx.y;
    #pragma unroll
    for (int i = 0; i < 4; ++i) {
        int k = k0 + ty + i * 8, m = m0 + tx;
        tile[ty + i * 8][tx] = (k < K && m < M) ? src[(size_t)k * M + m] : 0.f;
    }
    __syncthreads();
    #pragma unroll
    for (int i = 0; i < 4; ++i) {
        int m = m0 + ty + i * 8, k = k0 + tx;
        dst[(size_t)m * Kp + k] = f2bf(tile[tx][ty + i * 8]);
    }
}

// ======== weight prep: qkv(3) + o + f1 + f2; LAYERS via blockIdx.y ========
__global__ __launch_bounds__(256)
void prep_layer_w(const float* __restrict__ bqA, const float* __restrict__ bkA,
                  const float* __restrict__ bvA, const float* __restrict__ boA,
                  const float* __restrict__ f1A, const float* __restrict__ f2A,
                  short* __restrict__ qkvT, short* __restrict__ oT,
                  short* __restrict__ f1T, short* __restrict__ f2T)
{
    __shared__ float tile[32][33];
    const size_t L = blockIdx.y;
    const float* bq = bqA + L * HH * HH;
    const float* bk = bkA + L * HH * HH;
    const float* bv = bvA + L * HH * HH;
    const float* bo = boA + L * HH * HH;
    const float* f1 = f1A + L * HH * FF_;
    const float* f2 = f2A + L * FF_ * HH;
    short* qT = qkvT + L * 3 * HH * HH;
    short* oT2 = oT + L * HH * HH;
    short* f1T2 = f1T + L * HH * FF_;
    short* f2T2 = f2T + L * FF_ * HH;

    int id = blockIdx.x;
    const float* src; short* dst; int K, M, tm, tk;
    if (id < 1728) {
        const int mat = id / 576, r = id % 576;
        src = mat == 0 ? bq : (mat == 1 ? bk : bv);
        dst = qT + (size_t)mat * HH * HH;
        K = HH; M = HH; tm = r % 24; tk = r / 24;
    } else if (id < 2304) {
        const int r = id - 1728;
        src = bo; dst = oT2; K = HH; M = HH; tm = r % 24; tk = r / 24;
    } else if (id < 4608) {
        const int r = id - 2304;
        src = f1; dst = f1T2; K = HH; M = FF_; tm = r % 96; tk = r / 96;
    } else {
        const int r = id - 4608;
        src = f2; dst = f2T2; K = FF_; M = HH; tm = r % 24; tk = r / 24;
    }
    const int m0 = tm * 32, k0 = tk * 32;
    const int tx = threadIdx.x & 31, ty = threadIdx.x >> 5;
    #pragma unroll
    for (int i = 0; i < 4; ++i) {
        int k = k0 + ty + i * 8, m = m0 + tx;
        tile[ty + i * 8][tx] = src[(size_t)k * M + m];
    }
    __syncthreads();
    #pragma unroll
    for (int i = 0; i < 4; ++i) {
        int m = m0 + ty + i * 8, k = k0 + tx;
        dst[(size_t)m * K + k] = f2bf(tile[tx][ty + i * 8]);
    }
}

// ================= f32 -> bf16 =================
__global__ __launch_bounds__(256)
void cvt_bf16(const float* __restrict__ src, short* __restrict__ dst, int n4)
{
    int i = blockIdx.x * 256 + threadIdx.x;
    if (i >= n4) return;
    float4 v = reinterpret_cast<const float4*>(src)[i];
    short4v o = { f2bf(v.x), f2bf(v.y), f2bf(v.z), f2bf(v.w) };
    reinterpret_cast<short4v*>(dst)[i] = o;
}

// ================= features -> LN -> bf16 x [6144,512] =================
__global__ __launch_bounds__(512)
void build_x(const int* __restrict__ isf, const int* __restrict__ hloc,
             const int* __restrict__ psf,
             const float* __restrict__ dayE, const float* __restrict__ timeE,
             const float* __restrict__ dowE, const float* __restrict__ wdE,
             const float* __restrict__ locE,
             const float* __restrict__ g, const float* __restrict__ b2,
             short* __restrict__ xb)
{
    const int tok = blockIdx.x;
    const int b = tok / SS, s = tok % SS;
    const int tid = threadIdx.x;
    __shared__ float red[512];
    const int* f;
    int loc = -1;
    if (s < HIST) { f = isf + (b * HIST + s) * 6; loc = hloc[b * HIST + s]; }
    else          { f = psf + (b * PRED + (s - HIST)) * 6; }
    float val = 0.f;
    if (tid < DIN) {
        int c = tid;
        if      (c < 64)  val = dayE[f[0] * 64 + c];
        else if (c < 128) val = timeE[f[1] * 64 + (c - 64)];
        else if (c < 192) val = dowE[f[3] * 64 + (c - 128)];
        else if (c < 224) val = wdE[f[4] * 32 + (c - 192)];
        else if (c == 224) val = (float)f[5];
        else val = (loc >= 0) ? locE[(size_t)loc * 256 + (c - 225)] : 0.f;
    }
    red[tid] = (tid < DIN) ? val : 0.f;
    __syncthreads();
    for (int o = 256; o > 0; o >>= 1) { if (tid < o) red[tid] += red[tid + o]; __syncthreads(); }
    float mean = red[0] / (float)DIN;
    __syncthreads();
    float d = (tid < DIN) ? (val - mean) : 0.f;
    red[tid] = d * d;
    __syncthreads();
    for (int o = 256; o > 0; o >>= 1) { if (tid < o) red[tid] += red[tid + o]; __syncthreads(); }
    float rstd = rsqrtf(red[0] / (float)DIN + 1e-5f);
    if (tid < DINP)
        xb[(size_t)tok * DINP + tid] =
            (tid < DIN) ? f2bf((val - mean) * rstd * g[tid] + b2[tid]) : (short)0;
}

// ====== LayerNorm(768), wave-per-row, bf16 in/out: out = LN(in1+in2) =======
__global__ __launch_bounds__(256)
void ln768b(short* __restrict__ out, const short* __restrict__ in1,
            const short* __restrict__ in2,
            const float* __restrict__ g, const float* __restrict__ b2,
            float eps)
{
    const int w = threadIdx.x >> 6, lane = threadIdx.x & 63;
    const int row = blockIdx.x * 4 + w;
    float t[12];
    float sum = 0.f;
    #pragma unroll
    for (int i = 0; i < 3; ++i) {
        const int c = i * 256 + lane * 4;
        short4v a = *(const short4v*)&in1[(size_t)row * HH + c];
        short4v b = *(const short4v*)&in2[(size_t)row * HH + c];
        t[i * 4 + 0] = bf2f(a.x) + bf2f(b.x);
        t[i * 4 + 1] = bf2f(a.y) + bf2f(b.y);
        t[i * 4 + 2] = bf2f(a.z) + bf2f(b.z);
        t[i * 4 + 3] = bf2f(a.w) + bf2f(b.w);
        sum += t[i*4] + t[i*4+1] + t[i*4+2] + t[i*4+3];
    }
    #pragma unroll
    for (int d = 1; d < 64; d <<= 1) sum += __shfl_xor(sum, d);
    const float mean = sum * (1.f / 768.f);
    float p2 = 0.f;
    #pragma unroll
    for (int i = 0; i < 12; ++i) { float d = t[i] - mean; p2 += d * d; }
    #pragma unroll
    for (int d = 1; d < 64; d <<= 1) p2 += __shfl_xor(p2, d);
    const float rstd = rsqrtf(p2 * (1.f / 768.f) + eps);
    #pragma unroll
    for (int i = 0; i < 3; ++i) {
        const int c = i * 256 + lane * 4;
        float4 gg = *(const float4*)&g[c];
        float4 bb = *(const float4*)&b2[c];
        short4v ob = { f2bf((t[i*4+0] - mean) * rstd * gg.x + bb.x),
                       f2bf((t[i*4+1] - mean) * rstd * gg.y + bb.y),
                       f2bf((t[i*4+2] - mean) * rstd * gg.z + bb.z),
                       f2bf((t[i*4+3] - mean) * rstd * gg.w + bb.w) };
        *(short4v*)&out[(size_t)row * HH + c] = ob;
    }
}

// ====== fused double LN: out = LN2(LN1(in1+in2) + pos + tt) ================
__global__ __launch_bounds__(256)
void ln2_fused(short* __restrict__ out, const short* __restrict__ in1,
               const short* __restrict__ in2,
               const float* __restrict__ pos, const float* __restrict__ tt,
               const float* __restrict__ g1, const float* __restrict__ b1,
               const float* __restrict__ g2, const float* __restrict__ b2)
{
    const int w = threadIdx.x >> 6, lane = threadIdx.x & 63;
    const int row = blockIdx.x * 4 + w;
    const int s = row % SS;
    float t[12];
    float sum = 0.f;
    #pragma unroll
    for (int i = 0; i < 3; ++i) {
        const int c = i * 256 + lane * 4;
        short4v a = *(const short4v*)&in1[(size_t)row * HH + c];
        short4v b = *(const short4v*)&in2[(size_t)row * HH + c];
        t[i*4+0] = bf2f(a.x) + bf2f(b.x);
        t[i*4+1] = bf2f(a.y) + bf2f(b.y);
        t[i*4+2] = bf2f(a.z) + bf2f(b.z);
        t[i*4+3] = bf2f(a.w) + bf2f(b.w);
        sum += t[i*4] + t[i*4+1] + t[i*4+2] + t[i*4+3];
    }
    #pragma unroll
    for (int d = 1; d < 64; d <<= 1) sum += __shfl_xor(sum, d);
    float mean = sum * (1.f / 768.f);
    float p2 = 0.f;
    #pragma unroll
    for (int i = 0; i < 12; ++i) { float d = t[i] - mean; p2 += d * d; }
    #pragma unroll
    for (int d = 1; d < 64; d <<= 1) p2 += __shfl_xor(p2, d);
    float rstd = rsqrtf(p2 * (1.f / 768.f) + 1e-5f);
    sum = 0.f;
    #pragma unroll
    for (int i = 0; i < 3; ++i) {
        const int c = i * 256 + lane * 4;
        float4 gg = *(const float4*)&g1[c];
        float4 bb = *(const float4*)&b1[c];
        float4 pp = *(const float4*)&pos[(size_t)s * HH + c];
        float4 tz = *(const float4*)&tt[c];
        t[i*4+0] = (t[i*4+0] - mean) * rstd * gg.x + bb.x + pp.x + tz.x;
        t[i*4+1] = (t[i*4+1] - mean) * rstd * gg.y + bb.y + pp.y + tz.y;
        t[i*4+2] = (t[i*4+2] - mean) * rstd * gg.z + bb.z + pp.z + tz.z;
        t[i*4+3] = (t[i*4+3] - mean) * rstd * gg.w + bb.w + pp.w + tz.w;
        sum += t[i*4] + t[i*4+1] + t[i*4+2] + t[i*4+3];
    }
    #pragma unroll
    for (int d = 1; d < 64; d <<= 1) sum += __shfl_xor(sum, d);
    mean = sum * (1.f / 768.f);
    p2 = 0.f;
    #pragma unroll
    for (int i = 0; i < 12; ++i) { float d = t[i] - mean; p2 += d * d; }
    #pragma unroll
    for (int d = 1; d < 64; d <<= 1) p2 += __shfl_xor(p2, d);
    rstd = rsqrtf(p2 * (1.f / 768.f) + 1e-12f);
    #pragma unroll
    for (int i = 0; i < 3; ++i) {
        const int c = i * 256 + lane * 4;
        float4 gg = *(const float4*)&g2[c];
        float4 bb = *(const float4*)&b2[c];
        short4v ob = { f2bf((t[i*4+0] - mean) * rstd * gg.x + bb.x),
                       f2bf((t[i*4+1] - mean) * rstd * gg.y + bb.y),
                       f2bf((t[i*4+2] - mean) * rstd * gg.z + bb.z),
                       f2bf((t[i*4+3] - mean) * rstd * gg.w + bb.w) };
        *(short4v*)&out[(size_t)row * HH + c] = ob;
    }
}

// ==== row gather: dst[r] = src[(r/dstGroup)*srcGroup + srcOff + r%dstGroup] =
__global__ void gather_rows_b16(const short* __restrict__ src, short* __restrict__ dst,
                                int D, int srcGroup, int srcOff, int dstGroup)
{
    const int r = blockIdx.x;
    const int b = r / dstGroup, t = r % dstGroup;
    const int srow = b * srcGroup + srcOff + t;
    for (int c = threadIdx.x; c < D; c += blockDim.x)
        dst[(size_t)r * D + c] = src[(size_t)srow * D + c];
}

// ================= gate (bf16 input) =================
__global__ __launch_bounds__(256)
void gate_kernel(const short* __restrict__ Xb, const float* __restrict__ Wg,
                 const float* __restrict__ bg, float* __restrict__ out)
{
    const int row = blockIdx.x;
    const int tid = threadIdx.x;
    float a[NE_] = {};
    for (int k = tid; k < HH; k += 256) {
        float xv = bf2f(Xb[(size_t)row * HH + k]);
        #pragma unroll
        for (int e = 0; e < NE_; ++e) a[e] = fmaf(xv, Wg[k * NE_ + e], a[e]);
    }
    __shared__ float red[256];
    #pragma unroll
    for (int e = 0; e < NE_; ++e) {
        red[tid] = a[e]; __syncthreads();
        for (int o = 128; o > 0; o >>= 1) { if (tid < o) red[tid] += red[tid + o]; __syncthreads(); }
        if (tid == 0) out[(size_t)row * NE_ + e] = red[0] + bg[e];
        __syncthreads();
    }
}

__global__ void gate_softmax(float* __restrict__ gate)
{
    const int r = blockIdx.x * blockDim.x + threadIdx.x;
    if (r >= BB * PRED) return;
    float* p = gate + (size_t)r * NE_;
    float mx = p[0];
    for (int e = 1; e < NE_; ++e) mx = fmaxf(mx, p[e]);
    float s = 0.f, v[NE_];
    for (int e = 0; e < NE_; ++e) { v[e] = __expf(p[e] - mx); s += v[e]; }
    for (int e = 0; e < NE_; ++e) p[e] = v[e] / s;
}

// ============ MoE gated reduce: futm += sum_e g[e]*eo[row][e*768+c] ========
__global__ __launch_bounds__(256)
void moe_reduce(const float* __restrict__ eo, const float* __restrict__ gp,
                float* __restrict__ futm)
{
    const int row = blockIdx.x;
    float g[NE_];
    #pragma unroll
    for (int e = 0; e < NE_; ++e) g[e] = gp[row * NE_ + e];
    for (int c = threadIdx.x; c < HH; c += 256) {
        float s = futm[(size_t)row * HH + c];
        #pragma unroll
        for (int e = 0; e < NE_; ++e)
            s = fmaf(g[e], eo[(size_t)row * (NE_ * HH) + e * HH + c], s);
        futm[(size_t)row * HH + c] = s;
    }
}

// ================= host =================
extern "C" void kernel_launch(void* const* d_in, const int* in_sizes, int n_in,
                              void* d_out, int out_size, void* d_ws, size_t ws_size,
                              hipStream_t stream)
{
    const int*   isf   = (const int*)  d_in[0];
    const int*   hloc  = (const int*)  d_in[1];
    const int*   psf   = (const int*)  d_in[2];
    const float* dayE  = (const float*)d_in[3];
    const float* timeE = (const float*)d_in[4];
    const float* dowE  = (const float*)d_in[5];
    const float* wdE   = (const float*)d_in[6];
    const float* locE  = (const float*)d_in[7];
    const float* ln_g  = (const float*)d_in[8];
    const float* ln_b  = (const float*)d_in[9];
    const float* inpW  = (const float*)d_in[10];
    const float* inpB  = (const float*)d_in[11];
    const float* resW  = (const float*)d_in[12];
    const float* resB  = (const float*)d_in[13];
    const float* saqW  = (const float*)d_in[14];
    const float* sakW  = (const float*)d_in[15];
    const float* savW  = (const float*)d_in[16];
    const float* saoW  = (const float*)d_in[17];
    const float* saqB  = (const float*)d_in[18];
    const float* sakB  = (const float*)d_in[19];
    const float* savB  = (const float*)d_in[20];
    const float* saoB  = (const float*)d_in[21];
    const float* salnG = (const float*)d_in[22];
    const float* salnB = (const float*)d_in[23];
    const float* posE  = (const float*)d_in[24];
    const float* ttE   = (const float*)d_in[25];
    const float* belnG = (const float*)d_in[26];
    const float* belnB = (const float*)d_in[27];
    const float* bqW   = (const float*)d_in[28];
    const float* bkW   = (const float*)d_in[29];
    const float* bvW   = (const float*)d_in[30];
    const float* boW   = (const float*)d_in[31];
    const float* bqB   = (const float*)d_in[32];
    const float* bkB   = (const float*)d_in[33];
    const float* bvB   = (const float*)d_in[34];
    const float* boB   = (const float*)d_in[35];
    const float* balnG = (const float*)d_in[36];
    const float* balnB = (const float*)d_in[37];
    const float* bf1W  = (const float*)d_in[38];
    const float* bf1B  = (const float*)d_in[39];
    const float* bf2W  = (const float*)d_in[40];
    const float* bf2B  = (const float*)d_in[41];
    const float* bflnG = (const float*)d_in[42];
    const float* bflnB = (const float*)d_in[43];
    const float* moeW  = (const float*)d_in[44];
    const float* moeB  = (const float*)d_in[45];
    const float* gateW = (const float*)d_in[46];
    const float* gateB = (const float*)d_in[47];
    const float* outW  = (const float*)d_in[48];
    const float* outB  = (const float*)d_in[49];

    const int N6 = BB * SS;            // 6144
    const int NF = BB * PRED;          // 768

    char* base = (char*)d_ws;
    size_t off = 0;
    auto alloc = [&](size_t bytes) -> void* {
        void* p = base + off;
        off = (off + bytes + 255) & ~(size_t)255;
        return p;
    };

    short* xb   = (short*)alloc((size_t)N6 * DINP * 2);
    short* pb   = (short*)alloc((size_t)N6 * HH * 2);   // proj out / SA residual
    short* ab   = (short*)alloc((size_t)N6 * HH * 2);   // post-attn LN out
    short* Ob   = (short*)alloc((size_t)N6 * HH * 2);
    short* hcur = (short*)alloc((size_t)N6 * HH * 2);
    // --- contiguous trio reused as overlay after encoder (75.5MB) ---
    short* QKVb = (short*)alloc((size_t)N6 * 3 * HH * 2);
    short* C16  = (short*)alloc((size_t)N6 * HH * 2);
    short* ffb  = (short*)alloc((size_t)N6 * FF_ * 2);
    // ----------------------------------------------------------------
    short* inpWt  = (short*)alloc((size_t)HH * DINP * 2);
    short* resWt  = (short*)alloc((size_t)HH * DINP * 2);
    short* saWt   = (short*)alloc((size_t)3 * HH * HH * 2);
    short* saoWt  = (short*)alloc((size_t)HH * HH * 2);
    short* lqkvWt = (short*)alloc((size_t)3 * HH * HH * 2);
    short* loWt   = (short*)alloc((size_t)HH * HH * 2);
    short* lf1Wt  = (short*)alloc((size_t)FF_ * HH * 2);
    short* lf2Wt  = (short*)alloc((size_t)HH * FF_ * 2);
    float* futm   = (float*)alloc((size_t)NF * HH * 4);
    float* futg   = (float*)alloc((size_t)NF * NE_ * 4);
    // tail (layer-12 future-only) buffers, N=1024 rows
    short* Og   = (short*)alloc((size_t)NT * HH * 2);
    short* hg   = (short*)alloc((size_t)NT * HH * 2);
    short* Cg   = (short*)alloc((size_t)NT * HH * 2);
    short* ag   = (short*)alloc((size_t)NT * HH * 2);
    short* hfg  = (short*)alloc((size_t)NT * HH * 2);
    short* ffg  = (short*)alloc((size_t)NT * FF_ * 2);

    const size_t perL = ((size_t)3*HH*HH + (size_t)HH*HH + (size_t)HH*FF_ + (size_t)FF_*HH) * 2;
    short* LqkvA = nullptr; short* LoA = nullptr; short* Lf1A = nullptr; short* Lf2A = nullptr;
    bool upfront = false;
    if (ws_size > off + 12 * perL + (32u << 20)) {
        LqkvA = (short*)alloc((size_t)12 * 3 * HH * HH * 2);
        LoA   = (short*)alloc((size_t)12 * HH * HH * 2);
        Lf1A  = (short*)alloc((size_t)12 * HH * FF_ * 2);
        Lf2A  = (short*)alloc((size_t)12 * FF_ * HH * 2);
        upfront = true;
    }

    // overlay (post-encoder) inside QKVb..ffb
    short* outWt = QKVb;                              // [40064][768]
    short* moeWt = outWt + (size_t)VVP * HH;          // [6144][768]
    short* futhb = moeWt + (size_t)NE_ * HH * HH;
    short* futxb = futhb + (size_t)NF * HH;
    short* futmb = futxb + (size_t)NF * DINP;
    float* eoF   = (float*)pb;                        // [768][6144] f32

    // ---- features + input LN -> bf16 x ----
    build_x<<<N6, 512, 0, stream>>>(isf, hloc, psf, dayE, timeE, dowE, wdE, locE,
                                    ln_g, ln_b, xb);

    // ---- upfront weight prep ----
    dim3 tb(32, 8);
    transpose_cvt_b<<<dim3(HH/32, DINP/32, 1), tb, 0, stream>>>(inpW, inpWt, DIN, HH, DINP, 0, 0);
    transpose_cvt_b<<<dim3(HH/32, DINP/32, 1), tb, 0, stream>>>(resW, resWt, DIN, HH, DINP, 0, 0);
    transpose_cvt_b<<<dim3(HH/32, HH/32, 1), tb, 0, stream>>>(saqW, saWt,                   HH, HH, HH, 0, 0);
    transpose_cvt_b<<<dim3(HH/32, HH/32, 1), tb, 0, stream>>>(sakW, saWt + (size_t)HH*HH,   HH, HH, HH, 0, 0);
    transpose_cvt_b<<<dim3(HH/32, HH/32, 1), tb, 0, stream>>>(savW, saWt + (size_t)2*HH*HH, HH, HH, HH, 0, 0);
    transpose_cvt_b<<<dim3(HH/32, HH/32, 1), tb, 0, stream>>>(saoW, saoWt, HH, HH, HH, 0, 0);
    if (upfront)
        prep_layer_w<<<dim3(6912, 12), 256, 0, stream>>>(
            bqW, bkW, bvW, boW, bf1W, bf2W, LqkvA, LoA, Lf1A, Lf2A);

    // ---- proj = LN(x) @ inpW -> pb (bf16) ----
    gemm_bf16<5, false><<<dim3(HH/128, N6/128), 256, 0, stream>>>(
        xb, inpWt, inpB, nullptr, nullptr, pb, DINP, HH, HH);

    // ---- SA block (16 heads, hd=48) ----
    gemm_bf16<5, false><<<dim3(3*HH/128, N6/128), 256, 0, stream>>>(
        pb, saWt, saqB, sakB, savB, QKVb, HH, 3*HH, 3*HH);
    attn_mfma<48><<<BB*16*6, 256, 0, stream>>>(
        QKVb, QKVb + HH, QKVb + 2*HH, Ob, 16, 3*HH, 3*HH, HH,
        1.f / sqrtf(48.f), 0, 6, SS, SS);
    gemm_bf16<5, false><<<dim3(HH/128, N6/128), 256, 0, stream>>>(
        Ob, saoWt, saoB, nullptr, nullptr, C16, HH, HH, HH);
    ln2_fused<<<N6/4, 256, 0, stream>>>(hcur, C16, pb, posE, ttE,
                                        salnG, salnB, belnG, belnB);

    // ---- 12 encoder layers (last layer: future-rows-only tail) ----
    for (int i = 0; i < NL; ++i) {
        const size_t bo = (size_t)i * HH;
        const short* wQ; const short* wO; const short* wF1; const short* wF2;
        if (upfront) {
            wQ  = LqkvA + (size_t)i * 3 * HH * HH;
            wO  = LoA   + (size_t)i * HH * HH;
            wF1 = Lf1A  + (size_t)i * HH * FF_;
            wF2 = Lf2A  + (size_t)i * FF_ * HH;
        } else {
            prep_layer_w<<<dim3(6912, 1), 256, 0, stream>>>(
                bqW + (size_t)i*HH*HH, bkW + (size_t)i*HH*HH, bvW + (size_t)i*HH*HH,
                boW + (size_t)i*HH*HH, bf1W + (size_t)i*HH*FF_, bf2W + (size_t)i*FF_*HH,
                lqkvWt, loWt, lf1Wt, lf2Wt);
            wQ = lqkvWt; wO = loWt; wF1 = lf1Wt; wF2 = lf2Wt;
        }

        if (i < NL - 1) {
            gemm_bf16<5, false><<<dim3(3*HH/128, N6/128), 256, 0, stream>>>(
                hcur, wQ, bqB + bo, bkB + bo, bvB + bo, QKVb, HH, 3*HH, 3*HH);
            attn_mfma<64><<<BB*12*6, 256, 0, stream>>>(
                QKVb, QKVb + HH, QKVb + 2*HH, Ob, 12, 3*HH, 3*HH, HH,
                0.125f, 0, 6, SS, SS);
            gemm_bf16<5, false><<<dim3(HH/128, N6/128), 256, 0, stream>>>(
                Ob, wO, boB + bo, nullptr, nullptr, C16, HH, HH, HH);
            ln768b<<<N6/4, 256, 0, stream>>>(ab, C16, hcur, balnG + bo, balnB + bo, 1e-12f);
            gemm_bf16<4, false><<<dim3(FF_/128, N6/128), 256, 0, stream>>>(
                ab, wF1, bf1B + (size_t)i * FF_, nullptr, nullptr, ffb, HH, FF_, FF_);
            gemm_bf16<5, false><<<dim3(HH/128, N6/128), 256, 0, stream>>>(
                ffb, wF2, bf2B + bo, nullptr, nullptr, C16, FF_, HH, HH);
            ln768b<<<N6/4, 256, 0, stream>>>(hcur, C16, ab, bflnG + bo, bflnB + bo, 1e-12f);
        } else {
            // last layer: Q only for tail rows; K/V for ALL tokens
            gather_rows_b16<<<NT, 256, 0, stream>>>(hcur, hg, HH, SS, 320, 64);
            gemm_bf16<5, false><<<dim3(2*HH/128, N6/128), 256, 0, stream>>>(
                hcur, wQ + (size_t)HH*HH, bkB + bo, bvB + bo, bvB + bo,
                QKVb, HH, 2*HH, 2*HH);
            gemm_bf16<5, false><<<dim3(HH/128, NT/128), 256, 0, stream>>>(
                hg, wQ, bqB + bo, nullptr, nullptr, ag, HH, HH, HH);
            attn_mfma<64><<<BB*12*1, 256, 0, stream>>>(
                ag, QKVb, QKVb + HH, Og, 12, 2*HH, HH, HH,
                0.125f, 0, 1, 64, 64);
            gemm_bf16<5, false><<<dim3(HH/128, NT/128), 256, 0, stream>>>(
                Og, wO, boB + bo, nullptr, nullptr, Cg, HH, HH, HH);
            ln768b<<<NT/4, 256, 0, stream>>>(ag, Cg, hg, balnG + bo, balnB + bo, 1e-12f);
            gemm_bf16<4, false><<<dim3(FF_/128, NT/128), 256, 0, stream>>>(
                ag, wF1, bf1B + (size_t)i * FF_, nullptr, nullptr, ffg, HH, FF_, FF_);
            gemm_bf16<5, false><<<dim3(HH/128, NT/128), 256, 0, stream>>>(
                ffg, wF2, bf2B + bo, nullptr, nullptr, Cg, FF_, HH, HH);
            ln768b<<<NT/4, 256, 0, stream>>>(hfg, Cg, ag, bflnG + bo, bflnB + bo, 1e-12f);
        }
    }

    // ---- future slice: hfg rows b*64 + 16 + t  (t = 0..47) ----
    gather_rows_b16<<<NF, 256, 0, stream>>>(hfg, futhb, HH, 64, 16, PRED);
    gather_rows_b16<<<NF, 256, 0, stream>>>(xb, futxb, DINP, SS, HIST, PRED);

    // ---- residual path (f32 accumulator) ----
    gemm_bf16<0, false><<<dim3(HH/128, NF/128), 256, 0, stream>>>(
        futxb, resWt, resB, nullptr, nullptr, futm, DINP, HH, HH);

    // ---- gate ----
    gate_kernel<<<NF, 256, 0, stream>>>(futhb, gateW, gateB, futg);
    gate_softmax<<<3, 256, 0, stream>>>(futg);

    // ---- MoE: 8 experts fused -> eoF (pb region, dead) ----
    transpose_cvt_b<<<dim3(HH/32, HH/32, NE_), tb, 0, stream>>>(
        moeW, moeWt, HH, HH, HH, (size_t)HH*HH, (size_t)HH*HH);
    gemm_bf16<1, true><<<dim3(NE_*HH/128, NF/128), 256, 0, stream>>>(
        futhb, moeWt, moeB, nullptr, nullptr, eoF, HH, NE_*HH, NE_*HH);
    moe_reduce<<<NF, 256, 0, stream>>>(eoF, futg, futm);

    // ---- head: logits for future tokens ----
    {
        int n4 = (int)((size_t)NF * HH / 4);
        cvt_bf16<<<(n4 + 255) / 256, 256, 0, stream>>>(futm, futmb, n4);
    }
    transpose_cvt_b<<<dim3(VVP/32, HH/32, 1), tb, 0, stream>>>(
        outW, outWt, HH, VV, HH, 0, 0);
    gemm_bf16<0, true><<<dim3(VVP/128, NF/128), 256, 0, stream>>>(
        futmb, outWt, outB, nullptr, nullptr, (float*)d_out, HH, VV, VV);
}